// Round 3
// baseline (113.059 us; speedup 1.0000x reference)
//
#include <hip/hip_runtime.h>
#include <hip/hip_bf16.h>

#define TPB 256
#define VPT 8
#define TILE (TPB * VPT)      // 2048
#define NDAT 16384            // N = T-1
#define NTILES (NDAT / TILE)  // 8
#define TLEN 16385

__global__ __launch_bounds__(TPB) void vpl_kernel(
    const float* __restrict__ x, const float* __restrict__ params,
    float* __restrict__ out, int B) {
  const int b = blockIdx.x;
  const int tid = threadIdx.x;
  const int lane = tid & 63;
  const int wid = tid >> 6;

  const float r = params[0];
  const float ny = params[1];
  const bool rhalf = (r == 0.5f);

  const float* __restrict__ xr = x + (size_t)b * TLEN;

  float* out_coeffs = out;                                   // 2*B
  float* out_xhat = out + (size_t)2 * B + (size_t)b * NDAT;  // B*N
  float* out_res = out + (size_t)2 * B + (size_t)B * NDAT + (size_t)b * NDAT;
  float* out_r2 = out + (size_t)2 * B + (size_t)2 * B * NDAT;  // B

  __shared__ float wt[4];        // per-wave scan totals
  __shared__ double sred[4][5];  // per-wave reduction partials
  __shared__ float cbc[2];       // broadcast coeffs

  double carry = 0.0;  // running exclusive prefix across tiles
  double s_u = 0.0, s_u2 = 0.0, s_u15 = 0.0, s_xu = 0.0, s_xv = 0.0;

  // ---------------- Phase 1: scan + reductions, stage u in res slot ----------
  for (int k = 0; k < NTILES; ++k) {
    const int base = k * TILE + tid * VPT;  // element index in [0, NDAT)
    float xs[VPT + 1];
#pragma unroll
    for (int j = 0; j <= VPT; ++j) xs[j] = xr[base + j];  // max idx 16384, OK

    float run[VPT];
    float acc = 0.f;
#pragma unroll
    for (int j = 0; j < VPT; ++j) {
      acc += 0.5f * (xs[j] + xs[j + 1]);
      run[j] = acc;  // thread-local inclusive scan of inc
    }
    const float total = acc;

    // wave-level inclusive scan of per-thread totals
    float t = total;
#pragma unroll
    for (int d = 1; d < 64; d <<= 1) {
      float o = __shfl_up(t, d, 64);
      if (lane >= d) t += o;
    }
    if (lane == 63) wt[wid] = t;
    __syncthreads();

    float woff = 0.f, ttot = 0.f;
#pragma unroll
    for (int w = 0; w < 4; ++w) {
      float v = wt[w];
      ttot += v;
      if (w < wid) woff += v;
    }
    const float pre = woff + (t - total);  // exclusive prefix within block
    const double ubase = carry + (double)ny;

    float uu[VPT];
#pragma unroll
    for (int j = 0; j < VPT; ++j) {
      const double ud = ubase + (double)(pre + run[j]);
      uu[j] = (float)ud;
      const double v = rhalf ? sqrt(ud) : pow(ud, (double)r);
      const double xd = (double)xs[j + 1];
      s_u += ud;
      s_u2 += ud * ud;
      s_u15 += ud * v;
      s_xu += xd * ud;
      s_xv += xd * v;
    }
    // stage u in the res output region (same thread re-reads same addrs later)
    *reinterpret_cast<float4*>(out_res + base) =
        make_float4(uu[0], uu[1], uu[2], uu[3]);
    *reinterpret_cast<float4*>(out_res + base + 4) =
        make_float4(uu[4], uu[5], uu[6], uu[7]);

    carry += (double)ttot;
    __syncthreads();  // wt reused next tile
  }

  // ---------------- Block reduction of the 5 fp64 sums -----------------------
  {
    double vals[5] = {s_u, s_u2, s_u15, s_xu, s_xv};
#pragma unroll
    for (int i = 0; i < 5; ++i) {
      double v = vals[i];
#pragma unroll
      for (int d = 32; d >= 1; d >>= 1) v += __shfl_down(v, d, 64);
      vals[i] = v;
    }
    if (lane == 0) {
#pragma unroll
      for (int i = 0; i < 5; ++i) sred[wid][i] = vals[i];
    }
  }
  __syncthreads();

  if (tid == 0) {
    double g[5];
#pragma unroll
    for (int i = 0; i < 5; ++i)
      g[i] = sred[0][i] + sred[1][i] + sred[2][i] + sred[3][i];
    const double g11 = g[0];  // sum u       (= G[1][1] when r=0.5)
    const double g00 = g[1];  // sum u^2     (= G[0][0])
    const double g01 = g[2];  // sum u^{1+r} (= G[0][1])
    const double b0 = g[3];   // sum xd*u
    const double b1 = g[4];   // sum xd*u^r

    // Replicate jnp.linalg.pinv: SVD of (2 x 16384) fp32 matrix with default
    // rcond = 10 * max(M,N) * eps_fp32 = 10 * 16384 * 2^-23 = 0.01953125.
    // Singular values <= rcond*sigma1 are dropped.
    const double tr = g00 + g11;
    const double det = g00 * g11 - g01 * g01;
    const double disc = sqrt(fmax(tr * tr - 4.0 * det, 0.0));
    const double l1 = 0.5 * (tr + disc);
    const double l2 = (l1 > 0.0) ? fmax(det / l1, 0.0) : 0.0;
    const double s1 = sqrt(fmax(l1, 0.0));
    const double s2 = sqrt(l2);
    const double rcond = 0.01953125;

    double c0, c1;
    if (s2 > rcond * s1) {
      // rank-2: normal equations == full pinv
      c0 = (g11 * b0 - g01 * b1) / det;
      c1 = (g00 * b1 - g01 * b0) / det;
    } else if (s1 > 0.0) {
      // rank-1 truncated pinv: coeffs = ((b . u1)/l1) * u1
      // u1 ~ [l1 - g11, g01], normalized
      double w0 = l1 - g11, w1 = g01;
      double nrm = sqrt(w0 * w0 + w1 * w1);
      double e0, e1;
      if (nrm > 0.0) {
        e0 = w0 / nrm;
        e1 = w1 / nrm;
      } else {
        e0 = 1.0;
        e1 = 0.0;
      }
      const double gam = (b0 * e0 + b1 * e1) / l1;
      c0 = gam * e0;
      c1 = gam * e1;
    } else {
      c0 = 0.0;
      c1 = 0.0;
    }
    out_coeffs[2 * b] = (float)c0;
    out_coeffs[2 * b + 1] = (float)c1;
    cbc[0] = (float)c0;
    cbc[1] = (float)c1;
  }
  __syncthreads();
  const float c0 = cbc[0];
  const float c1 = cbc[1];

  // ---------------- Phase 2: x_hat, res, r2 ----------------------------------
  double r2 = 0.0;
  for (int k = 0; k < NTILES; ++k) {
    const int base = k * TILE + tid * VPT;
    const float4 u0 = *reinterpret_cast<const float4*>(out_res + base);
    const float4 u1v = *reinterpret_cast<const float4*>(out_res + base + 4);
    float uu[VPT] = {u0.x, u0.y, u0.z, u0.w, u1v.x, u1v.y, u1v.z, u1v.w};
    float xd[VPT];
#pragma unroll
    for (int j = 0; j < VPT; ++j) xd[j] = xr[base + 1 + j];

    float xh[VPT], rs[VPT];
#pragma unroll
    for (int j = 0; j < VPT; ++j) {
      const float vh = rhalf ? sqrtf(uu[j]) : powf(uu[j], r);
      xh[j] = c0 * uu[j] + c1 * vh;
      rs[j] = xd[j] - xh[j];
      r2 += (double)rs[j] * (double)rs[j];
    }
    *reinterpret_cast<float4*>(out_xhat + base) =
        make_float4(xh[0], xh[1], xh[2], xh[3]);
    *reinterpret_cast<float4*>(out_xhat + base + 4) =
        make_float4(xh[4], xh[5], xh[6], xh[7]);
    *reinterpret_cast<float4*>(out_res + base) =
        make_float4(rs[0], rs[1], rs[2], rs[3]);
    *reinterpret_cast<float4*>(out_res + base + 4) =
        make_float4(rs[4], rs[5], rs[6], rs[7]);
  }

  // reduce r2
#pragma unroll
  for (int d = 32; d >= 1; d >>= 1) r2 += __shfl_down(r2, d, 64);
  if (lane == 0) sred[wid][0] = r2;
  __syncthreads();
  if (tid == 0)
    out_r2[b] = (float)(sred[0][0] + sred[1][0] + sred[2][0] + sred[3][0]);
}

extern "C" void kernel_launch(void* const* d_in, const int* in_sizes, int n_in,
                              void* d_out, int out_size, void* d_ws,
                              size_t ws_size, hipStream_t stream) {
  const float* x = (const float*)d_in[0];
  const float* params = (const float*)d_in[1];
  float* out = (float*)d_out;
  const int B = in_sizes[0] / TLEN;  // 512
  vpl_kernel<<<dim3(B), dim3(TPB), 0, stream>>>(x, params, out, B);
}

// Round 5
// 110.211 us; speedup vs baseline: 1.0258x; 1.0258x over previous
//
#include <hip/hip_runtime.h>
#include <hip/hip_bf16.h>

#define TPB 1024
#define VPT 8
#define TILE (TPB * VPT)      // 8192
#define NDAT 16384            // N = T-1
#define NTILES (NDAT / TILE)  // 2
#define TLEN 16385
#define NWAVES (TPB / 64)     // 16

__global__ __launch_bounds__(TPB) void vpl_kernel(
    const float* __restrict__ x, const float* __restrict__ params,
    float* __restrict__ out, int B) {
  const int b = blockIdx.x;
  const int tid = threadIdx.x;
  const int lane = tid & 63;
  const int wid = tid >> 6;

  const float r = params[0];
  const float ny = params[1];
  const bool rhalf = (r == 0.5f);

  const float* __restrict__ xr = x + (size_t)b * TLEN;

  float* out_coeffs = out;                                   // 2*B
  float* out_xhat = out + (size_t)2 * B + (size_t)b * NDAT;  // B*N
  float* out_res = out + (size_t)2 * B + (size_t)B * NDAT + (size_t)b * NDAT;
  float* out_r2 = out + (size_t)2 * B + (size_t)2 * B * NDAT;  // B

  __shared__ float wt[NWAVES];        // per-wave scan totals
  __shared__ double sred[NWAVES][5];  // per-wave reduction partials
  __shared__ float cbc[2];            // broadcast coeffs

  double carry = 0.0;      // running exclusive prefix across tiles
  double off[NTILES];      // this thread's exclusive-prefix base per tile
  double s_u = 0.0, s_u2 = 0.0, s_u15 = 0.0, s_xu = 0.0, s_xv = 0.0;

  // ---------------- Phase 1: scan + fp64 Gram/rhs reductions -----------------
#pragma unroll
  for (int k = 0; k < NTILES; ++k) {
    const int base = k * TILE + tid * VPT;  // element index in [0, NDAT)
    float xs[VPT + 1];
#pragma unroll
    for (int j = 0; j <= VPT; ++j) xs[j] = xr[base + j];  // max idx 16384, OK

    float run[VPT];
    float acc = 0.f;
#pragma unroll
    for (int j = 0; j < VPT; ++j) {
      acc += 0.5f * (xs[j] + xs[j + 1]);
      run[j] = acc;  // thread-local inclusive scan of trapezoid increments
    }
    const float total = acc;

    // wave-level inclusive scan of per-thread totals
    float t = total;
#pragma unroll
    for (int d = 1; d < 64; d <<= 1) {
      float o = __shfl_up(t, d, 64);
      if (lane >= d) t += o;
    }
    if (lane == 63) wt[wid] = t;
    __syncthreads();

    float woff = 0.f, ttot = 0.f;
#pragma unroll
    for (int w = 0; w < NWAVES; ++w) {
      float v = wt[w];
      ttot += v;
      if (w < wid) woff += v;
    }
    const float pre = woff + (t - total);  // exclusive prefix within block
    off[k] = carry + (double)ny + (double)pre;

#pragma unroll
    for (int j = 0; j < VPT; ++j) {
      const double ud = off[k] + (double)run[j];
      const double v = rhalf ? sqrt(ud) : pow(ud, (double)r);
      const double xd = (double)xs[j + 1];
      s_u += ud;
      s_u2 += ud * ud;
      s_u15 += ud * v;
      s_xu += xd * ud;
      s_xv += xd * v;
    }
    carry += (double)ttot;
    if (k + 1 < NTILES) __syncthreads();  // wt reused next tile
  }

  // ---------------- Block reduction of the 5 fp64 sums -----------------------
  {
    double vals[5] = {s_u, s_u2, s_u15, s_xu, s_xv};
#pragma unroll
    for (int i = 0; i < 5; ++i) {
      double v = vals[i];
#pragma unroll
      for (int d = 32; d >= 1; d >>= 1) v += __shfl_down(v, d, 64);
      vals[i] = v;
    }
    if (lane == 0) {
#pragma unroll
      for (int i = 0; i < 5; ++i) sred[wid][i] = vals[i];
    }
  }
  __syncthreads();

  if (tid == 0) {
    double g[5];
#pragma unroll
    for (int i = 0; i < 5; ++i) {
      double s = 0.0;
#pragma unroll
      for (int w = 0; w < NWAVES; ++w) s += sred[w][i];
      g[i] = s;
    }
    const double g11 = g[0];  // sum u       (= G[1][1] when r=0.5)
    const double g00 = g[1];  // sum u^2     (= G[0][0])
    const double g01 = g[2];  // sum u^{1+r} (= G[0][1])
    const double b0 = g[3];   // sum xd*u
    const double b1 = g[4];   // sum xd*u^r

    // Replicate jnp.linalg.pinv: SVD of (2 x 16384) fp32 matrix with default
    // rcond = 10 * max(M,N) * eps_fp32 = 0.01953125; sigma <= rcond*s1 dropped.
    const double tr = g00 + g11;
    const double det = g00 * g11 - g01 * g01;
    const double disc = sqrt(fmax(tr * tr - 4.0 * det, 0.0));
    const double l1 = 0.5 * (tr + disc);
    const double l2 = (l1 > 0.0) ? fmax(det / l1, 0.0) : 0.0;
    const double s1 = sqrt(fmax(l1, 0.0));
    const double s2 = sqrt(l2);
    const double rcond = 0.01953125;

    double c0, c1;
    if (s2 > rcond * s1) {
      // rank-2: normal equations == full pinv
      c0 = (g11 * b0 - g01 * b1) / det;
      c1 = (g00 * b1 - g01 * b0) / det;
    } else if (s1 > 0.0) {
      // rank-1 truncated pinv: coeffs = ((b . u1)/l1) * u1, u1 ~ [l1-g11, g01]
      double w0 = l1 - g11, w1 = g01;
      double nrm = sqrt(w0 * w0 + w1 * w1);
      double e0, e1;
      if (nrm > 0.0) {
        e0 = w0 / nrm;
        e1 = w1 / nrm;
      } else {
        e0 = 1.0;
        e1 = 0.0;
      }
      const double gam = (b0 * e0 + b1 * e1) / l1;
      c0 = gam * e0;
      c1 = gam * e1;
    } else {
      c0 = 0.0;
      c1 = 0.0;
    }
    out_coeffs[2 * b] = (float)c0;
    out_coeffs[2 * b + 1] = (float)c1;
    cbc[0] = (float)c0;
    cbc[1] = (float)c1;
  }
  __syncthreads();
  const float c0 = cbc[0];
  const float c1 = cbc[1];

  // ---------------- Phase 2: recompute u, emit x_hat, res, r2 ----------------
  double r2 = 0.0;
#pragma unroll
  for (int k = 0; k < NTILES; ++k) {
    const int base = k * TILE + tid * VPT;
    float xs[VPT + 1];
#pragma unroll
    for (int j = 0; j <= VPT; ++j) xs[j] = xr[base + j];  // L2/L3-hot

    float acc = 0.f;
    float xh[VPT], rs[VPT];
#pragma unroll
    for (int j = 0; j < VPT; ++j) {
      acc += 0.5f * (xs[j] + xs[j + 1]);  // bit-identical to phase 1 run[j]
      const float uu = (float)(off[k] + (double)acc);
      const float vh = rhalf ? sqrtf(uu) : powf(uu, r);
      xh[j] = c0 * uu + c1 * vh;
      rs[j] = xs[j + 1] - xh[j];
      r2 += (double)rs[j] * (double)rs[j];
    }
    *reinterpret_cast<float4*>(out_xhat + base) =
        make_float4(xh[0], xh[1], xh[2], xh[3]);
    *reinterpret_cast<float4*>(out_xhat + base + 4) =
        make_float4(xh[4], xh[5], xh[6], xh[7]);
    *reinterpret_cast<float4*>(out_res + base) =
        make_float4(rs[0], rs[1], rs[2], rs[3]);
    *reinterpret_cast<float4*>(out_res + base + 4) =
        make_float4(rs[4], rs[5], rs[6], rs[7]);
  }

  // reduce r2
#pragma unroll
  for (int d = 32; d >= 1; d >>= 1) r2 += __shfl_down(r2, d, 64);
  if (lane == 0) sred[wid][0] = r2;
  __syncthreads();
  if (tid == 0) {
    double s = 0.0;
#pragma unroll
    for (int w = 0; w < NWAVES; ++w) s += sred[w][0];
    out_r2[b] = (float)s;
  }
}

extern "C" void kernel_launch(void* const* d_in, const int* in_sizes, int n_in,
                              void* d_out, int out_size, void* d_ws,
                              size_t ws_size, hipStream_t stream) {
  const float* x = (const float*)d_in[0];
  const float* params = (const float*)d_in[1];
  float* out = (float*)d_out;
  const int B = in_sizes[0] / TLEN;  // 512
  vpl_kernel<<<dim3(B), dim3(TPB), 0, stream>>>(x, params, out, B);
}

// Round 7
// 107.931 us; speedup vs baseline: 1.0475x; 1.0211x over previous
//
#include <hip/hip_runtime.h>
#include <hip/hip_bf16.h>

#define TPB 1024
#define VPT 8
#define TILE (TPB * VPT)      // 8192
#define NDAT 16384            // N = T-1
#define NTILES (NDAT / TILE)  // 2
#define TLEN 16385
#define NWAVES (TPB / 64)     // 16

__global__ __launch_bounds__(TPB) void vpl_kernel(
    const float* __restrict__ x, const float* __restrict__ params,
    float* __restrict__ out, int B) {
  const int b = blockIdx.x;
  const int tid = threadIdx.x;
  const int lane = tid & 63;
  const int wid = tid >> 6;

  const float r = params[0];
  const float ny = params[1];
  const bool rhalf = (r == 0.5f);

  const float* __restrict__ xr = x + (size_t)b * TLEN;

  float* out_coeffs = out;                                   // 2*B
  float* out_xhat = out + (size_t)2 * B + (size_t)b * NDAT;  // B*N
  float* out_res = out + (size_t)2 * B + (size_t)B * NDAT + (size_t)b * NDAT;
  float* out_r2 = out + (size_t)2 * B + (size_t)2 * B * NDAT;  // B

  __shared__ float wt[NTILES][NWAVES];  // per-wave scan totals (dbuf: no reuse barrier)
  __shared__ double sred[NWAVES][5];    // per-wave reduction partials
  __shared__ float cbc[2];              // broadcast coeffs

  double carry = 0.0;   // running exclusive prefix across tiles (fp64 carry)
  float offf[NTILES];   // this thread's fp32 prefix base per tile
  // fp32 per-thread partial sums (16 elements each -> ~1e-6 rel error, fine)
  float s_u = 0.f, s_u2 = 0.f, s_u15 = 0.f, s_xu = 0.f, s_xv = 0.f;

  // ---------------- Phase 1: scan + Gram/rhs partial sums (all-fp32 inner) ---
#pragma unroll
  for (int k = 0; k < NTILES; ++k) {
    const int base = k * TILE + tid * VPT;  // element index in [0, NDAT)
    float xs[VPT + 1];
#pragma unroll
    for (int j = 0; j <= VPT; ++j) xs[j] = xr[base + j];  // max idx 16384, OK

    float run[VPT];
    float acc = 0.f;
#pragma unroll
    for (int j = 0; j < VPT; ++j) {
      acc += 0.5f * (xs[j] + xs[j + 1]);
      run[j] = acc;  // thread-local inclusive scan of trapezoid increments
    }
    const float total = acc;

    // wave-level inclusive scan of per-thread totals
    float t = total;
#pragma unroll
    for (int d = 1; d < 64; d <<= 1) {
      float o = __shfl_up(t, d, 64);
      if (lane >= d) t += o;
    }
    if (lane == 63) wt[k][wid] = t;
    __syncthreads();

    float woff = 0.f, ttot = 0.f;
#pragma unroll
    for (int w = 0; w < NWAVES; ++w) {
      float v = wt[k][w];
      ttot += v;
      if (w < wid) woff += v;
    }
    const float pre = woff + (t - total);  // exclusive prefix within block
    offf[k] = (float)(carry + (double)ny + (double)pre);

#pragma unroll
    for (int j = 0; j < VPT; ++j) {
      const float uu = offf[k] + run[j];  // fp32; identical expr in phase 2
      const float vh = rhalf ? sqrtf(uu) : powf(uu, r);
      const float xd = xs[j + 1];
      s_u += uu;
      s_u2 = fmaf(uu, uu, s_u2);
      s_u15 = fmaf(uu, vh, s_u15);
      s_xu = fmaf(xd, uu, s_xu);
      s_xv = fmaf(xd, vh, s_xv);
    }
    carry += (double)ttot;
  }

  // ---------------- Block reduction of the 5 sums (fp64 tree) ----------------
  {
    double vals[5] = {(double)s_u, (double)s_u2, (double)s_u15, (double)s_xu,
                      (double)s_xv};
#pragma unroll
    for (int i = 0; i < 5; ++i) {
      double v = vals[i];
#pragma unroll
      for (int d = 32; d >= 1; d >>= 1) v += __shfl_down(v, d, 64);
      vals[i] = v;
    }
    if (lane == 0) {
#pragma unroll
      for (int i = 0; i < 5; ++i) sred[wid][i] = vals[i];
    }
  }
  __syncthreads();

  if (tid == 0) {
    double g[5];
#pragma unroll
    for (int i = 0; i < 5; ++i) {
      double s = 0.0;
#pragma unroll
      for (int w = 0; w < NWAVES; ++w) s += sred[w][i];
      g[i] = s;
    }
    const double g11 = g[0];  // sum u       (= G[1][1] when r=0.5)
    const double g00 = g[1];  // sum u^2     (= G[0][0])
    const double g01 = g[2];  // sum u^{1+r} (= G[0][1])
    const double b0 = g[3];   // sum xd*u
    const double b1 = g[4];   // sum xd*u^r

    // Replicate jnp.linalg.pinv: SVD of (2 x 16384) fp32 matrix with default
    // rcond = 10 * max(M,N) * eps_fp32 = 0.01953125; sigma <= rcond*s1 dropped.
    const double tr = g00 + g11;
    const double det = g00 * g11 - g01 * g01;
    const double disc = sqrt(fmax(tr * tr - 4.0 * det, 0.0));
    const double l1 = 0.5 * (tr + disc);
    const double l2 = (l1 > 0.0) ? fmax(det / l1, 0.0) : 0.0;
    const double s1 = sqrt(fmax(l1, 0.0));
    const double s2 = sqrt(l2);
    const double rcond = 0.01953125;

    double c0, c1;
    if (s2 > rcond * s1) {
      // rank-2: normal equations == full pinv
      c0 = (g11 * b0 - g01 * b1) / det;
      c1 = (g00 * b1 - g01 * b0) / det;
    } else if (s1 > 0.0) {
      // rank-1 truncated pinv: coeffs = ((b . u1)/l1) * u1, u1 ~ [l1-g11, g01]
      double w0 = l1 - g11, w1 = g01;
      double nrm = sqrt(w0 * w0 + w1 * w1);
      double e0, e1;
      if (nrm > 0.0) {
        e0 = w0 / nrm;
        e1 = w1 / nrm;
      } else {
        e0 = 1.0;
        e1 = 0.0;
      }
      const double gam = (b0 * e0 + b1 * e1) / l1;
      c0 = gam * e0;
      c1 = gam * e1;
    } else {
      c0 = 0.0;
      c1 = 0.0;
    }
    out_coeffs[2 * b] = (float)c0;
    out_coeffs[2 * b + 1] = (float)c1;
    cbc[0] = (float)c0;
    cbc[1] = (float)c1;
  }
  __syncthreads();
  const float c0 = cbc[0];
  const float c1 = cbc[1];

  // ---------------- Phase 2: recompute u, emit x_hat, res, r2 ----------------
  float r2f = 0.f;  // per-thread fp32 partial (16 residual squares)
#pragma unroll
  for (int k = 0; k < NTILES; ++k) {
    const int base = k * TILE + tid * VPT;
    float xs[VPT + 1];
#pragma unroll
    for (int j = 0; j <= VPT; ++j) xs[j] = xr[base + j];  // L1/L2-hot

    float acc = 0.f;
    float xh[VPT], rs[VPT];
#pragma unroll
    for (int j = 0; j < VPT; ++j) {
      acc += 0.5f * (xs[j] + xs[j + 1]);   // bit-identical to phase-1 run[j]
      const float uu = offf[k] + acc;      // bit-identical to phase-1 uu
      const float vh = rhalf ? sqrtf(uu) : powf(uu, r);
      xh[j] = fmaf(c0, uu, c1 * vh);
      rs[j] = xs[j + 1] - xh[j];
      r2f = fmaf(rs[j], rs[j], r2f);
    }
    *reinterpret_cast<float4*>(out_xhat + base) =
        make_float4(xh[0], xh[1], xh[2], xh[3]);
    *reinterpret_cast<float4*>(out_xhat + base + 4) =
        make_float4(xh[4], xh[5], xh[6], xh[7]);
    *reinterpret_cast<float4*>(out_res + base) =
        make_float4(rs[0], rs[1], rs[2], rs[3]);
    *reinterpret_cast<float4*>(out_res + base + 4) =
        make_float4(rs[4], rs[5], rs[6], rs[7]);
  }

  // reduce r2 (fp64 tree over fp32 per-thread partials)
  double r2 = (double)r2f;
#pragma unroll
  for (int d = 32; d >= 1; d >>= 1) r2 += __shfl_down(r2, d, 64);
  if (lane == 0) sred[wid][0] = r2;
  __syncthreads();
  if (tid == 0) {
    double s = 0.0;
#pragma unroll
    for (int w = 0; w < NWAVES; ++w) s += sred[w][0];
    out_r2[b] = (float)s;
  }
}

extern "C" void kernel_launch(void* const* d_in, const int* in_sizes, int n_in,
                              void* d_out, int out_size, void* d_ws,
                              size_t ws_size, hipStream_t stream) {
  const float* x = (const float*)d_in[0];
  const float* params = (const float*)d_in[1];
  float* out = (float*)d_out;
  const int B = in_sizes[0] / TLEN;  // 512
  vpl_kernel<<<dim3(B), dim3(TPB), 0, stream>>>(x, params, out, B);
}